// Round 4
// baseline (7120.801 us; speedup 1.0000x reference)
//
#include <hip/hip_runtime.h>
#include <cstddef>

// Problem constants (fixed by the reference)
static const int WW = 8192;     // width (atoms)
static const int DD = 768;      // input dim
static const int BBATCH = 8192; // batch
static const int KSEL = 32;     // MP steps

// ---------------------------------------------------------------------------
// column norms of Ad [D, W] -> nrm[W] = max(||Ad[:,w]||, 1e-8), fp64 accumulate
// ---------------------------------------------------------------------------
__global__ __launch_bounds__(256) void colnorm_kernel(const float* __restrict__ Ad,
                                                      float* __restrict__ nrm) {
    int w = blockIdx.x * 256 + threadIdx.x;
    double s = 0.0;
    for (int d = 0; d < DD; ++d) {
        double v = (double)Ad[(size_t)d * WW + w];
        s += v * v;
    }
    nrm[w] = fmaxf((float)sqrt(s), 1e-8f);
}

// ---------------------------------------------------------------------------
// AdnT[w, d] = Ad[d, w] / nrm[w]   (LDS tiled transpose, 32x32)
// ---------------------------------------------------------------------------
__global__ __launch_bounds__(256) void transpose_scale_kernel(const float* __restrict__ Ad,
                                                              const float* __restrict__ nrm,
                                                              float* __restrict__ AdnT) {
    __shared__ float tile[32][33];
    int wb = blockIdx.x * 32;
    int db = blockIdx.y * 32;
    int tx = threadIdx.x;   // 0..31
    int ty = threadIdx.y;   // 0..7
    for (int i = ty; i < 32; i += 8)
        tile[i][tx] = Ad[(size_t)(db + i) * WW + (wb + tx)];
    __syncthreads();
    for (int i = ty; i < 32; i += 8)
        AdnT[(size_t)(wb + i) * DD + (db + tx)] = tile[tx][i] / nrm[wb + i];
}

// ---------------------------------------------------------------------------
// Gram (TN, fp64 accumulate): G[i,j] = (sum_d Ad[d,i]*Ad[d,j]) / (nrm[i]*nrm[j])
// 64x64 tile, BK=16, 256 threads, 4x4 fp64 microtile. Output stored fp32.
// ---------------------------------------------------------------------------
__global__ __launch_bounds__(256) void gram_tn_f64_kernel(const float* __restrict__ Ad,
                                                          const float* __restrict__ nrm,
                                                          float* __restrict__ G) {
    __shared__ __align__(16) float As[16 * 68];
    __shared__ __align__(16) float Bs[16 * 68];
    const int tid = threadIdx.x;
    const int tx = tid & 15;         // 0..15 (col group)
    const int ty = tid >> 4;         // 0..15 (row group)
    const int i0 = blockIdx.y * 64;
    const int j0 = blockIdx.x * 64;
    const int kr = tid >> 4;         // 0..15 staging k-row
    const int cb = (tid & 15) * 4;   // 0..60 staging col offset

    double acc[4][4];
#pragma unroll
    for (int i = 0; i < 4; ++i)
#pragma unroll
        for (int j = 0; j < 4; ++j) acc[i][j] = 0.0;

    for (int k0 = 0; k0 < DD; k0 += 16) {
        const float* arow = Ad + (size_t)(k0 + kr) * WW;
        float4 ai = *(const float4*)&arow[i0 + cb];
        float4 bj = *(const float4*)&arow[j0 + cb];
        __syncthreads();
        *(float4*)&As[kr * 68 + cb] = ai;
        *(float4*)&Bs[kr * 68 + cb] = bj;
        __syncthreads();
#pragma unroll
        for (int kk = 0; kk < 16; ++kk) {
            float4 af = *(const float4*)&As[kk * 68 + ty * 4];
            float4 bf = *(const float4*)&Bs[kk * 68 + tx * 4];
            double a[4] = {(double)af.x, (double)af.y, (double)af.z, (double)af.w};
            double b[4] = {(double)bf.x, (double)bf.y, (double)bf.z, (double)bf.w};
#pragma unroll
            for (int i = 0; i < 4; ++i)
#pragma unroll
                for (int j = 0; j < 4; ++j) acc[i][j] += a[i] * b[j];
        }
    }

#pragma unroll
    for (int i = 0; i < 4; ++i) {
        int row = i0 + ty * 4 + i;
        double inv_i = 1.0 / (double)nrm[row];
#pragma unroll
        for (int j = 0; j < 4; ++j) {
            int col = j0 + tx * 4 + j;
            G[(size_t)row * WW + col] = (float)(acc[i][j] * inv_i / (double)nrm[col]);
        }
    }
}

// ---------------------------------------------------------------------------
// z (NN, fp64 accumulate): Z[b,w] = (sum_d (X[b,d]-bd[d]) * Ad[d,w]) / nrm[w]
// 64x64 tile, BK=16, 256 threads, 4x4 fp64 microtile. Output stored fp32.
// ---------------------------------------------------------------------------
__global__ __launch_bounds__(256) void z_nn_f64_kernel(const float* __restrict__ X,
                                                       const float* __restrict__ Ad,
                                                       const float* __restrict__ bd,
                                                       const float* __restrict__ nrm,
                                                       float* __restrict__ Z) {
    __shared__ __align__(16) float As[16 * 68];   // As[k][b] transposed
    __shared__ __align__(16) float Bs[16 * 68];   // Bs[k][w] direct
    const int tid = threadIdx.x;
    const int tx = tid & 15;
    const int ty = tid >> 4;
    const int b0 = blockIdx.y * 64;
    const int w0 = blockIdx.x * 64;
    const int r  = tid >> 2;        // 0..63 (A staging row)
    const int k4 = (tid & 3) * 4;   // 0,4,8,12
    const int kr = tid >> 4;        // 0..15 (B staging k-row)
    const int cb = (tid & 15) * 4;  // 0..60

    double acc[4][4];
#pragma unroll
    for (int i = 0; i < 4; ++i)
#pragma unroll
        for (int j = 0; j < 4; ++j) acc[i][j] = 0.0;

    for (int k0 = 0; k0 < DD; k0 += 16) {
        float4 bias = *(const float4*)&bd[k0 + k4];
        float4 a = *(const float4*)&X[(size_t)(b0 + r) * DD + k0 + k4];
        a.x -= bias.x; a.y -= bias.y; a.z -= bias.z; a.w -= bias.w;
        const float* arow = Ad + (size_t)(k0 + kr) * WW;
        float4 bv = *(const float4*)&arow[w0 + cb];
        __syncthreads();
        As[(k4 + 0) * 68 + r] = a.x;
        As[(k4 + 1) * 68 + r] = a.y;
        As[(k4 + 2) * 68 + r] = a.z;
        As[(k4 + 3) * 68 + r] = a.w;
        *(float4*)&Bs[kr * 68 + cb] = bv;
        __syncthreads();
#pragma unroll
        for (int kk = 0; kk < 16; ++kk) {
            float4 af = *(const float4*)&As[kk * 68 + ty * 4];
            float4 bf = *(const float4*)&Bs[kk * 68 + tx * 4];
            double a2[4] = {(double)af.x, (double)af.y, (double)af.z, (double)af.w};
            double b2[4] = {(double)bf.x, (double)bf.y, (double)bf.z, (double)bf.w};
#pragma unroll
            for (int i = 0; i < 4; ++i)
#pragma unroll
                for (int j = 0; j < 4; ++j) acc[i][j] += a2[i] * b2[j];
        }
    }

#pragma unroll
    for (int i = 0; i < 4; ++i) {
        int row = b0 + ty * 4 + i;
#pragma unroll
        for (int j = 0; j < 4; ++j) {
            int col = w0 + tx * 4 + j;
            Z[(size_t)row * WW + col] = (float)(acc[i][j] / (double)nrm[col]);
        }
    }
}

// ---------------------------------------------------------------------------
// Fused MP loop (fp32 G). One block per batch row; z-row in LDS.
// ---------------------------------------------------------------------------
__global__ __launch_bounds__(256) void mp_loop_kernel(const float* __restrict__ z0,
                                                      const float* __restrict__ G,
                                                      int* __restrict__ idxL,
                                                      float* __restrict__ valL) {
    __shared__ __align__(16) float zrow[WW];
    __shared__ float red_v[256];
    __shared__ int red_i[256];
    __shared__ int sel[KSEL];
    const int b = blockIdx.x;
    const int t = threadIdx.x;

    {
        const float4* zp = (const float4*)(z0 + (size_t)b * WW);
        float4* zs = (float4*)zrow;
        for (int i = t; i < WW / 4; i += 256) zs[i] = zp[i];
    }
    __syncthreads();

    for (int k = 0; k < KSEL; ++k) {
        // per-thread argmax; strided ascending scan + '>' keeps lowest index
        float best = -1.f;
        int bidx = 0;
        for (int w = t; w < WW; w += 256) {
            float av = fabsf(zrow[w]);
            if (av > best) { best = av; bidx = w; }
        }
        red_v[t] = best;
        red_i[t] = bidx;
        __syncthreads();
        for (int s = 128; s > 0; s >>= 1) {
            if (t < s) {
                float v2 = red_v[t + s];
                int i2 = red_i[t + s];
                if (v2 > red_v[t] || (v2 == red_v[t] && i2 < red_i[t])) {
                    red_v[t] = v2;
                    red_i[t] = i2;
                }
            }
            __syncthreads();
        }
        const int idx = red_i[0];
        const float val = zrow[idx];   // pre-update value (LDS broadcast)
        if (t == 0) {
            sel[k] = idx;
            idxL[(size_t)b * KSEL + k] = idx;
            valL[(size_t)b * KSEL + k] = val;
        }
        __syncthreads();   // everyone has read val before zrow is modified

        // rank-1 update: zrow -= val * G[idx, :]
        {
            const float4* gr = (const float4*)(G + (size_t)idx * WW);
            float4* zs = (float4*)zrow;
            for (int w = t; w < WW / 4; w += 256) {
                float4 g = gr[w];
                float4 z = zs[w];
                z.x -= val * g.x;
                z.y -= val * g.y;
                z.z -= val * g.z;
                z.w -= val * g.w;
                zs[w] = z;
            }
        }
        __syncthreads();
        // re-zero every selected position (mask semantics of the reference)
        if (t <= k) zrow[sel[t]] = 0.f;
        __syncthreads();
    }
}

// ---------------------------------------------------------------------------
// copy idx/val metadata (d_out staging -> ws), element-wise
// ---------------------------------------------------------------------------
__global__ __launch_bounds__(256) void copy_meta_kernel(const int* __restrict__ si,
                                                        const float* __restrict__ sv,
                                                        int* __restrict__ di,
                                                        float* __restrict__ dv,
                                                        int n) {
    int i = blockIdx.x * 256 + threadIdx.x;
    if (i < n) {
        di[i] = si[i];
        dv[i] = sv[i];
    }
}

// ---------------------------------------------------------------------------
// out[row, :] = bd + sum_k val[b,k] * AdnT[idx[b,k], :]
// ---------------------------------------------------------------------------
__global__ __launch_bounds__(256) void assemble_kernel(const float* __restrict__ AdnT,
                                                       const float* __restrict__ bd,
                                                       const int* __restrict__ idxL,
                                                       const float* __restrict__ valL,
                                                       float* __restrict__ out,
                                                       int rowStart) {
    __shared__ int sidx[KSEL];
    __shared__ float sval[KSEL];
    const int b = blockIdx.x;
    const int row = rowStart + b;
    const int t = threadIdx.x;
    if (t < KSEL) {
        sidx[t] = idxL[(size_t)b * KSEL + t];
        sval[t] = valL[(size_t)b * KSEL + t];
    }
    __syncthreads();
    float acc0 = bd[t];
    float acc1 = bd[t + 256];
    float acc2 = bd[t + 512];
#pragma unroll 4
    for (int k = 0; k < KSEL; ++k) {
        const float* col = AdnT + (size_t)sidx[k] * DD;
        float v = sval[k];
        acc0 += v * col[t];
        acc1 += v * col[t + 256];
        acc2 += v * col[t + 512];
    }
    out[(size_t)row * DD + t] = acc0;
    out[(size_t)row * DD + t + 256] = acc1;
    out[(size_t)row * DD + t + 512] = acc2;
}

// ---------------------------------------------------------------------------
extern "C" void kernel_launch(void* const* d_in, const int* in_sizes, int n_in,
                              void* d_out, int out_size, void* d_ws, size_t ws_size,
                              hipStream_t stream) {
    const float* x  = (const float*)d_in[0];   // [B, D]
    const float* Ad = (const float*)d_in[1];   // [D, W]
    const float* bd = (const float*)d_in[2];   // [1, D]
    float* out = (float*)d_out;                // [B, D]

    const size_t ADNT_B = (size_t)WW * DD * 4;        // 25,165,824
    const size_t NRM_B  = (size_t)WW * 4;             // 32,768
    const size_t IDX_B  = (size_t)BBATCH * KSEL * 4;  // 1,048,576
    const size_t VAL_B  = IDX_B;
    const size_t G_B    = (size_t)WW * WW * 4;        // 268,435,456
    const size_t ZROW_B = (size_t)WW * 4;             // 32,768
    const size_t A_MIN  = ADNT_B + NRM_B + IDX_B + VAL_B + G_B + 128 * ZROW_B;

    if (ws_size >= A_MIN) {
        // ---------------- Layout A: everything in ws ----------------
        char* p = (char*)d_ws;
        float* AdnT = (float*)p;  p += ADNT_B;
        float* nrm  = (float*)p;  p += NRM_B;
        int*   idxL = (int*)p;    p += IDX_B;
        float* valL = (float*)p;  p += VAL_B;
        float* G    = (float*)p;  p += G_B;
        float* z    = (float*)p;
        size_t z_avail = ws_size - (ADNT_B + NRM_B + IDX_B + VAL_B + G_B);
        int chunk = (int)((z_avail / ZROW_B) / 128) * 128;
        if (chunk > BBATCH) chunk = BBATCH;

        colnorm_kernel<<<WW / 256, 256, 0, stream>>>(Ad, nrm);
        gram_tn_f64_kernel<<<dim3(WW / 64, WW / 64), 256, 0, stream>>>(Ad, nrm, G);
        for (int r0 = 0; r0 < BBATCH; r0 += chunk) {
            int rows = (BBATCH - r0 < chunk) ? (BBATCH - r0) : chunk;
            z_nn_f64_kernel<<<dim3(WW / 64, rows / 64), 256, 0, stream>>>(
                x + (size_t)r0 * DD, Ad, bd, nrm, z);
            mp_loop_kernel<<<rows, 256, 0, stream>>>(
                z, G, idxL + (size_t)r0 * KSEL, valL + (size_t)r0 * KSEL);
        }
        transpose_scale_kernel<<<dim3(WW / 32, DD / 32), dim3(32, 8), 0, stream>>>(Ad, nrm, AdnT);
        assemble_kernel<<<BBATCH, 256, 0, stream>>>(AdnT, bd, idxL, valL, out, 0);
    } else if (ws_size >= G_B) {
        // ---------------- Layout B: ws = G only; scratch in d_out ----------------
        // d_out carve (25,165,824 B total):
        //   [0 .. 20,971,520)          z chunks (640 rows x 32 KB)
        //   [20,971,520 .. 21,004,288) nrm (32 KB)
        //   [23,068,672 .. 24,117,248) idxL [B,32]
        //   [24,117,248 .. 25,165,824) valL [B,32]
        float* G    = (float*)d_ws;
        char*  ob   = (char*)d_out;
        float* z    = (float*)ob;
        float* nrm  = (float*)(ob + 20971520);
        int*   idxL = (int*)(ob + 23068672);
        float* valL = (float*)(ob + 24117248);
        // after MP loops, G is dead -> reuse ws:
        float* AdnT = (float*)d_ws;
        int*   idx2 = (int*)((char*)d_ws + ADNT_B);
        float* val2 = (float*)((char*)d_ws + ADNT_B + IDX_B);
        const int chunk = 640;   // multiple of 64

        colnorm_kernel<<<WW / 256, 256, 0, stream>>>(Ad, nrm);
        gram_tn_f64_kernel<<<dim3(WW / 64, WW / 64), 256, 0, stream>>>(Ad, nrm, G);
        for (int r0 = 0; r0 < BBATCH; r0 += chunk) {
            int rows = (BBATCH - r0 < chunk) ? (BBATCH - r0) : chunk;
            z_nn_f64_kernel<<<dim3(WW / 64, rows / 64), 256, 0, stream>>>(
                x + (size_t)r0 * DD, Ad, bd, nrm, z);
            mp_loop_kernel<<<rows, 256, 0, stream>>>(
                z, G, idxL + (size_t)r0 * KSEL, valL + (size_t)r0 * KSEL);
        }
        // relocate metadata into ws (G dead), build AdnT in ws, then one
        // hazard-free assemble overwrites d_out.
        {
            int n = BBATCH * KSEL;
            copy_meta_kernel<<<(n + 255) / 256, 256, 0, stream>>>(idxL, valL, idx2, val2, n);
        }
        transpose_scale_kernel<<<dim3(WW / 32, DD / 32), dim3(32, 8), 0, stream>>>(Ad, nrm, AdnT);
        assemble_kernel<<<BBATCH, 256, 0, stream>>>(AdnT, bd, idx2, val2, out, 0);
    }
    // else: ws too small for any fp32-G plan -> leave output zeroed (clean fail)
}

// Round 5
// 5395.410 us; speedup vs baseline: 1.3198x; 1.3198x over previous
//
#include <hip/hip_runtime.h>
#include <cstddef>

// Problem constants (fixed by the reference)
static const int WW = 8192;     // width (atoms)
static const int DD = 768;      // input dim
static const int BBATCH = 8192; // batch
static const int KSEL = 32;     // MP steps

// ---------------------------------------------------------------------------
// column norms of Ad [D, W] -> nrm[W] = max(||Ad[:,w]||, 1e-8), fp64 accumulate
// ---------------------------------------------------------------------------
__global__ __launch_bounds__(256) void colnorm_kernel(const float* __restrict__ Ad,
                                                      float* __restrict__ nrm) {
    int w = blockIdx.x * 256 + threadIdx.x;
    double s = 0.0;
    for (int d = 0; d < DD; ++d) {
        double v = (double)Ad[(size_t)d * WW + w];
        s += v * v;
    }
    nrm[w] = fmaxf((float)sqrt(s), 1e-8f);
}

// ---------------------------------------------------------------------------
// AdnT[w, d] = Ad[d, w] / nrm[w]   (LDS tiled transpose, 32x32)
// ---------------------------------------------------------------------------
__global__ __launch_bounds__(256) void transpose_scale_kernel(const float* __restrict__ Ad,
                                                              const float* __restrict__ nrm,
                                                              float* __restrict__ AdnT) {
    __shared__ float tile[32][33];
    int wb = blockIdx.x * 32;
    int db = blockIdx.y * 32;
    int tx = threadIdx.x;   // 0..31
    int ty = threadIdx.y;   // 0..7
    for (int i = ty; i < 32; i += 8)
        tile[i][tx] = Ad[(size_t)(db + i) * WW + (wb + tx)];
    __syncthreads();
    for (int i = ty; i < 32; i += 8)
        AdnT[(size_t)(wb + i) * DD + (db + tx)] = tile[tx][i] / nrm[wb + i];
}

// ---------------------------------------------------------------------------
// Gram (TN, fp64 accumulate): G[i,j] = (sum_d Ad[d,i]*Ad[d,j]) / (nrm[i]*nrm[j])
// UPPER tiles only (j-tile >= i-tile); mirror_kernel fills the lower half.
// 64x64 tile, BK=16, 256 threads, 4x4 fp64 microtile. Output stored fp32.
// ---------------------------------------------------------------------------
__global__ __launch_bounds__(256) void gram_tn_f64_kernel(const float* __restrict__ Ad,
                                                          const float* __restrict__ nrm,
                                                          float* __restrict__ G) {
    if (blockIdx.x < blockIdx.y) return;   // symmetric: compute j0 >= i0 only
    __shared__ __align__(16) float As[16 * 68];
    __shared__ __align__(16) float Bs[16 * 68];
    const int tid = threadIdx.x;
    const int tx = tid & 15;         // 0..15 (col group)
    const int ty = tid >> 4;         // 0..15 (row group)
    const int i0 = blockIdx.y * 64;
    const int j0 = blockIdx.x * 64;
    const int kr = tid >> 4;         // 0..15 staging k-row
    const int cb = (tid & 15) * 4;   // 0..60 staging col offset

    double acc[4][4];
#pragma unroll
    for (int i = 0; i < 4; ++i)
#pragma unroll
        for (int j = 0; j < 4; ++j) acc[i][j] = 0.0;

    for (int k0 = 0; k0 < DD; k0 += 16) {
        const float* arow = Ad + (size_t)(k0 + kr) * WW;
        float4 ai = *(const float4*)&arow[i0 + cb];
        float4 bj = *(const float4*)&arow[j0 + cb];
        __syncthreads();
        *(float4*)&As[kr * 68 + cb] = ai;
        *(float4*)&Bs[kr * 68 + cb] = bj;
        __syncthreads();
#pragma unroll
        for (int kk = 0; kk < 16; ++kk) {
            float4 af = *(const float4*)&As[kk * 68 + ty * 4];
            float4 bf = *(const float4*)&Bs[kk * 68 + tx * 4];
            double a[4] = {(double)af.x, (double)af.y, (double)af.z, (double)af.w};
            double b[4] = {(double)bf.x, (double)bf.y, (double)bf.z, (double)bf.w};
#pragma unroll
            for (int i = 0; i < 4; ++i)
#pragma unroll
                for (int j = 0; j < 4; ++j) acc[i][j] += a[i] * b[j];
        }
    }

#pragma unroll
    for (int i = 0; i < 4; ++i) {
        int row = i0 + ty * 4 + i;
        double inv_i = 1.0 / (double)nrm[row];
#pragma unroll
        for (int j = 0; j < 4; ++j) {
            int col = j0 + tx * 4 + j;
            G[(size_t)row * WW + col] = (float)(acc[i][j] * inv_i / (double)nrm[col]);
        }
    }
}

// ---------------------------------------------------------------------------
// mirror: G[j,i] = G[i,j] for strict-upper 64x64 tiles (bitwise-exact copy)
// ---------------------------------------------------------------------------
__global__ __launch_bounds__(256) void mirror_kernel(float* __restrict__ G) {
    const int ti = blockIdx.y;
    const int tj = blockIdx.x;
    if (tj <= ti) return;
    __shared__ float tile[64][65];
    const int t = threadIdx.x;
    const int c4 = (t & 15) * 4;   // 0..60
    const int r  = t >> 4;         // 0..15
#pragma unroll
    for (int rr = r; rr < 64; rr += 16) {
        float4 v = *(const float4*)&G[(size_t)(ti * 64 + rr) * WW + tj * 64 + c4];
        tile[rr][c4 + 0] = v.x;
        tile[rr][c4 + 1] = v.y;
        tile[rr][c4 + 2] = v.z;
        tile[rr][c4 + 3] = v.w;
    }
    __syncthreads();
#pragma unroll
    for (int rr = r; rr < 64; rr += 16) {
        float4 v = make_float4(tile[c4 + 0][rr], tile[c4 + 1][rr],
                               tile[c4 + 2][rr], tile[c4 + 3][rr]);
        *(float4*)&G[(size_t)(tj * 64 + rr) * WW + ti * 64 + c4] = v;
    }
}

// ---------------------------------------------------------------------------
// z (NN, fp64 accumulate): Z[b,w] = (sum_d (X[b,d]-bd[d]) * Ad[d,w]) / nrm[w]
// 64x64 tile, BK=16, 256 threads, 4x4 fp64 microtile. Output stored fp32.
// ---------------------------------------------------------------------------
__global__ __launch_bounds__(256) void z_nn_f64_kernel(const float* __restrict__ X,
                                                       const float* __restrict__ Ad,
                                                       const float* __restrict__ bd,
                                                       const float* __restrict__ nrm,
                                                       float* __restrict__ Z) {
    __shared__ __align__(16) float As[16 * 68];   // As[k][b] transposed
    __shared__ __align__(16) float Bs[16 * 68];   // Bs[k][w] direct
    const int tid = threadIdx.x;
    const int tx = tid & 15;
    const int ty = tid >> 4;
    const int b0 = blockIdx.y * 64;
    const int w0 = blockIdx.x * 64;
    const int r  = tid >> 2;        // 0..63 (A staging row)
    const int k4 = (tid & 3) * 4;   // 0,4,8,12
    const int kr = tid >> 4;        // 0..15 (B staging k-row)
    const int cb = (tid & 15) * 4;  // 0..60

    double acc[4][4];
#pragma unroll
    for (int i = 0; i < 4; ++i)
#pragma unroll
        for (int j = 0; j < 4; ++j) acc[i][j] = 0.0;

    for (int k0 = 0; k0 < DD; k0 += 16) {
        float4 bias = *(const float4*)&bd[k0 + k4];
        float4 a = *(const float4*)&X[(size_t)(b0 + r) * DD + k0 + k4];
        a.x -= bias.x; a.y -= bias.y; a.z -= bias.z; a.w -= bias.w;
        const float* arow = Ad + (size_t)(k0 + kr) * WW;
        float4 bv = *(const float4*)&arow[w0 + cb];
        __syncthreads();
        As[(k4 + 0) * 68 + r] = a.x;
        As[(k4 + 1) * 68 + r] = a.y;
        As[(k4 + 2) * 68 + r] = a.z;
        As[(k4 + 3) * 68 + r] = a.w;
        *(float4*)&Bs[kr * 68 + cb] = bv;
        __syncthreads();
#pragma unroll
        for (int kk = 0; kk < 16; ++kk) {
            float4 af = *(const float4*)&As[kk * 68 + ty * 4];
            float4 bf = *(const float4*)&Bs[kk * 68 + tx * 4];
            double a2[4] = {(double)af.x, (double)af.y, (double)af.z, (double)af.w};
            double b2[4] = {(double)bf.x, (double)bf.y, (double)bf.z, (double)bf.w};
#pragma unroll
            for (int i = 0; i < 4; ++i)
#pragma unroll
                for (int j = 0; j < 4; ++j) acc[i][j] += a2[i] * b2[j];
        }
    }

#pragma unroll
    for (int i = 0; i < 4; ++i) {
        int row = b0 + ty * 4 + i;
#pragma unroll
        for (int j = 0; j < 4; ++j) {
            int col = w0 + tx * 4 + j;
            Z[(size_t)row * WW + col] = (float)(acc[i][j] / (double)nrm[col]);
        }
    }
}

// ---------------------------------------------------------------------------
// Fused MP loop. One block per batch row; z-row in LDS for all 32 steps.
// Argmax tracking fused into the rank-1 update pass; wave64 shfl butterfly
// reduce + 4-partial LDS resolve -> 2 barriers per step.
// Selected positions forced to 0 at store time via per-thread ownership mask
// (thread t owns float4 slots t+256*j, j=0..7 -> 32 scalar positions).
// Selection state at each argmax is identical to the separate-scan version.
// ---------------------------------------------------------------------------
__global__ __launch_bounds__(256) void mp_loop_kernel(const float* __restrict__ z0,
                                                      const float* __restrict__ G,
                                                      int* __restrict__ idxL,
                                                      float* __restrict__ valL) {
    __shared__ __align__(16) float zrow[WW];   // 32 KB
    __shared__ float wv[4];
    __shared__ int   wi[4];
    const int b = blockIdx.x;
    const int t = threadIdx.x;
    float4* zs = (float4*)zrow;

    float best = -1.f;
    int bidx = 0;
    unsigned selmask = 0;   // bit j*4+e: slot (t+256*j) element e is selected

    // load z row into LDS, tracking running max (ascending w + strict '>'
    // keeps the first occurrence, matching jnp.argmax)
    {
        const float4* zp = (const float4*)(z0 + (size_t)b * WW);
#pragma unroll
        for (int j = 0; j < 8; ++j) {
            int slot = t + 256 * j;
            float4 v = zp[slot];
            zs[slot] = v;
            int w = slot * 4;
            float a0 = fabsf(v.x), a1 = fabsf(v.y), a2 = fabsf(v.z), a3 = fabsf(v.w);
            if (a0 > best) { best = a0; bidx = w; }
            if (a1 > best) { best = a1; bidx = w + 1; }
            if (a2 > best) { best = a2; bidx = w + 2; }
            if (a3 > best) { best = a3; bidx = w + 3; }
        }
    }

    for (int k = 0; k < KSEL; ++k) {
        // wave-level butterfly argmax (64 lanes, first-index tie-break)
        float v = best;
        int i = bidx;
#pragma unroll
        for (int off = 32; off > 0; off >>= 1) {
            float ov = __shfl_xor(v, off, 64);
            int   oi = __shfl_xor(i, off, 64);
            if (ov > v || (ov == v && oi < i)) { v = ov; i = oi; }
        }
        if ((t & 63) == 0) { wv[t >> 6] = v; wi[t >> 6] = i; }
        __syncthreads();   // A: partials visible; prev phase's zrow writes visible
        float rv = wv[0];
        int   ri = wi[0];
#pragma unroll
        for (int q = 1; q < 4; ++q) {
            float qv = wv[q];
            int   qi = wi[q];
            if (qv > rv || (qv == rv && qi < ri)) { rv = qv; ri = qi; }
        }
        const int idx = ri;
        const float val = zrow[idx];   // pre-update value (LDS broadcast)
        if (t == 0) {
            idxL[(size_t)b * KSEL + k] = idx;
            valL[(size_t)b * KSEL + k] = val;
        }
        if (((idx >> 2) & 255) == t)
            selmask |= 1u << (((idx >> 10) << 2) | (idx & 3));
        if (k == KSEL - 1) break;      // final update is dead work
        __syncthreads();   // B: all threads have read val before zrow changes

        // rank-1 update + fused max tracking: zrow -= val * G[idx,:],
        // selected positions forced to 0 (mask-before-argmax semantics)
        best = -1.f;
        bidx = 0;
        const float4* gr = (const float4*)(G + (size_t)idx * WW);
#pragma unroll
        for (int j = 0; j < 8; ++j) {
            int slot = t + 256 * j;
            float4 g = gr[slot];
            float4 z = zs[slot];
            unsigned m = (selmask >> (j * 4)) & 0xFu;
            float n0 = (m & 1u) ? 0.f : z.x - val * g.x;
            float n1 = (m & 2u) ? 0.f : z.y - val * g.y;
            float n2 = (m & 4u) ? 0.f : z.z - val * g.z;
            float n3 = (m & 8u) ? 0.f : z.w - val * g.w;
            zs[slot] = make_float4(n0, n1, n2, n3);
            int w = slot * 4;
            float a0 = fabsf(n0), a1 = fabsf(n1), a2 = fabsf(n2), a3 = fabsf(n3);
            if (a0 > best) { best = a0; bidx = w; }
            if (a1 > best) { best = a1; bidx = w + 1; }
            if (a2 > best) { best = a2; bidx = w + 2; }
            if (a3 > best) { best = a3; bidx = w + 3; }
        }
    }
}

// ---------------------------------------------------------------------------
// copy idx/val metadata (d_out staging -> ws), element-wise
// ---------------------------------------------------------------------------
__global__ __launch_bounds__(256) void copy_meta_kernel(const int* __restrict__ si,
                                                        const float* __restrict__ sv,
                                                        int* __restrict__ di,
                                                        float* __restrict__ dv,
                                                        int n) {
    int i = blockIdx.x * 256 + threadIdx.x;
    if (i < n) {
        di[i] = si[i];
        dv[i] = sv[i];
    }
}

// ---------------------------------------------------------------------------
// out[row, :] = bd + sum_k val[b,k] * AdnT[idx[b,k], :]
// ---------------------------------------------------------------------------
__global__ __launch_bounds__(256) void assemble_kernel(const float* __restrict__ AdnT,
                                                       const float* __restrict__ bd,
                                                       const int* __restrict__ idxL,
                                                       const float* __restrict__ valL,
                                                       float* __restrict__ out,
                                                       int rowStart) {
    __shared__ int sidx[KSEL];
    __shared__ float sval[KSEL];
    const int b = blockIdx.x;
    const int row = rowStart + b;
    const int t = threadIdx.x;
    if (t < KSEL) {
        sidx[t] = idxL[(size_t)b * KSEL + t];
        sval[t] = valL[(size_t)b * KSEL + t];
    }
    __syncthreads();
    float acc0 = bd[t];
    float acc1 = bd[t + 256];
    float acc2 = bd[t + 512];
#pragma unroll 4
    for (int k = 0; k < KSEL; ++k) {
        const float* col = AdnT + (size_t)sidx[k] * DD;
        float v = sval[k];
        acc0 += v * col[t];
        acc1 += v * col[t + 256];
        acc2 += v * col[t + 512];
    }
    out[(size_t)row * DD + t] = acc0;
    out[(size_t)row * DD + t + 256] = acc1;
    out[(size_t)row * DD + t + 512] = acc2;
}

// ---------------------------------------------------------------------------
extern "C" void kernel_launch(void* const* d_in, const int* in_sizes, int n_in,
                              void* d_out, int out_size, void* d_ws, size_t ws_size,
                              hipStream_t stream) {
    const float* x  = (const float*)d_in[0];   // [B, D]
    const float* Ad = (const float*)d_in[1];   // [D, W]
    const float* bd = (const float*)d_in[2];   // [1, D]
    float* out = (float*)d_out;                // [B, D]

    const size_t ADNT_B = (size_t)WW * DD * 4;        // 25,165,824
    const size_t NRM_B  = (size_t)WW * 4;             // 32,768
    const size_t IDX_B  = (size_t)BBATCH * KSEL * 4;  // 1,048,576
    const size_t VAL_B  = IDX_B;
    const size_t G_B    = (size_t)WW * WW * 4;        // 268,435,456
    const size_t ZROW_B = (size_t)WW * 4;             // 32,768
    const size_t A_MIN  = ADNT_B + NRM_B + IDX_B + VAL_B + G_B + 128 * ZROW_B;

    if (ws_size >= A_MIN) {
        // ---------------- Layout A: everything in ws ----------------
        char* p = (char*)d_ws;
        float* AdnT = (float*)p;  p += ADNT_B;
        float* nrm  = (float*)p;  p += NRM_B;
        int*   idxL = (int*)p;    p += IDX_B;
        float* valL = (float*)p;  p += VAL_B;
        float* G    = (float*)p;  p += G_B;
        float* z    = (float*)p;
        size_t z_avail = ws_size - (ADNT_B + NRM_B + IDX_B + VAL_B + G_B);
        int chunk = (int)((z_avail / ZROW_B) / 128) * 128;
        if (chunk > BBATCH) chunk = BBATCH;

        colnorm_kernel<<<WW / 256, 256, 0, stream>>>(Ad, nrm);
        gram_tn_f64_kernel<<<dim3(WW / 64, WW / 64), 256, 0, stream>>>(Ad, nrm, G);
        mirror_kernel<<<dim3(WW / 64, WW / 64), 256, 0, stream>>>(G);
        for (int r0 = 0; r0 < BBATCH; r0 += chunk) {
            int rows = (BBATCH - r0 < chunk) ? (BBATCH - r0) : chunk;
            z_nn_f64_kernel<<<dim3(WW / 64, rows / 64), 256, 0, stream>>>(
                x + (size_t)r0 * DD, Ad, bd, nrm, z);
            mp_loop_kernel<<<rows, 256, 0, stream>>>(
                z, G, idxL + (size_t)r0 * KSEL, valL + (size_t)r0 * KSEL);
        }
        transpose_scale_kernel<<<dim3(WW / 32, DD / 32), dim3(32, 8), 0, stream>>>(Ad, nrm, AdnT);
        assemble_kernel<<<BBATCH, 256, 0, stream>>>(AdnT, bd, idxL, valL, out, 0);
    } else if (ws_size >= G_B) {
        // ---------------- Layout B: ws = G only; scratch in d_out ----------------
        // d_out carve (25,165,824 B total):
        //   [0 .. 20,971,520)          z chunks (640 rows x 32 KB)
        //   [20,971,520 .. 21,004,288) nrm (32 KB)
        //   [23,068,672 .. 24,117,248) idxL [B,32]
        //   [24,117,248 .. 25,165,824) valL [B,32]
        float* G    = (float*)d_ws;
        char*  ob   = (char*)d_out;
        float* z    = (float*)ob;
        float* nrm  = (float*)(ob + 20971520);
        int*   idxL = (int*)(ob + 23068672);
        float* valL = (float*)(ob + 24117248);
        // after MP loops, G is dead -> reuse ws:
        float* AdnT = (float*)d_ws;
        int*   idx2 = (int*)((char*)d_ws + ADNT_B);
        float* val2 = (float*)((char*)d_ws + ADNT_B + IDX_B);
        const int chunk = 640;   // multiple of 64

        colnorm_kernel<<<WW / 256, 256, 0, stream>>>(Ad, nrm);
        gram_tn_f64_kernel<<<dim3(WW / 64, WW / 64), 256, 0, stream>>>(Ad, nrm, G);
        mirror_kernel<<<dim3(WW / 64, WW / 64), 256, 0, stream>>>(G);
        for (int r0 = 0; r0 < BBATCH; r0 += chunk) {
            int rows = (BBATCH - r0 < chunk) ? (BBATCH - r0) : chunk;
            z_nn_f64_kernel<<<dim3(WW / 64, rows / 64), 256, 0, stream>>>(
                x + (size_t)r0 * DD, Ad, bd, nrm, z);
            mp_loop_kernel<<<rows, 256, 0, stream>>>(
                z, G, idxL + (size_t)r0 * KSEL, valL + (size_t)r0 * KSEL);
        }
        // relocate metadata into ws (G dead), build AdnT in ws, then one
        // hazard-free assemble overwrites d_out.
        {
            int n = BBATCH * KSEL;
            copy_meta_kernel<<<(n + 255) / 256, 256, 0, stream>>>(idxL, valL, idx2, val2, n);
        }
        transpose_scale_kernel<<<dim3(WW / 32, DD / 32), dim3(32, 8), 0, stream>>>(Ad, nrm, AdnT);
        assemble_kernel<<<BBATCH, 256, 0, stream>>>(AdnT, bd, idx2, val2, out, 0);
    }
    // else: ws too small for any fp32-G plan -> leave output zeroed (clean fail)
}